// Round 4
// baseline (416.106 us; speedup 1.0000x reference)
//
#include <hip/hip_runtime.h>

// GCN 2-layer forward for MI355X.
// R4: occupancy+ILP round.
//  - GEMM1: 782 blocks (64x128 tile, 2x2 waves of 32x64), reg double-buffered
//    fragment loads, fused fp32->fp16-split (hi + lo/1024, 3 MFMA products).
//  - GEMM2: 782 blocks (64x64 tile, 4 waves of 16x64), same structure.
//  - CSR padded to multiple-of-4 edges/node (norm=0 fills) -> tail-free agg.
//  - agg: 8-deep independent gather unroll, float2 lanes for F=128.

#define NNODES 50000
#define NEDGES 640000
#define NFEAT 512
#define NHID 128
#define NCLS 64

typedef _Float16 f16x8 __attribute__((ext_vector_type(8)));
typedef _Float16 f16x2 __attribute__((ext_vector_type(2)));
typedef float f32x4 __attribute__((ext_vector_type(4)));

__global__ void k_zero2(int* __restrict__ a, int* __restrict__ b, int n) {
  int i = blockIdx.x * blockDim.x + threadIdx.x;
  if (i < n) { a[i] = 0; b[i] = 0; }
}

__global__ void k_hist(const int* __restrict__ dst, int* __restrict__ indeg, int E) {
  int i = blockIdx.x * blockDim.x + threadIdx.x;
  if (i < E) atomicAdd(&indeg[dst[i]], 1);
}

__global__ void k_dinv(const int* __restrict__ indeg, float* __restrict__ dinv, int n) {
  int i = blockIdx.x * blockDim.x + threadIdx.x;
  if (i < n) dinv[i] = 1.0f / sqrtf((float)(indeg[i] + 1));
}

// Exclusive scan over n+1 slots of PADDED degree ((d+3)&~3); slot n -> total.
__global__ void k_scan_block(const int* __restrict__ indeg, int* __restrict__ row_start,
                             int* __restrict__ blocksum, int n) {
  __shared__ int sdata[256];
  int t = threadIdx.x;
  int base = blockIdx.x * 1024 + t * 4;
  int v[4];
#pragma unroll
  for (int j = 0; j < 4; ++j) {
    int idx = base + j;
    int d = (idx < n) ? indeg[idx] : 0;
    v[j] = (d + 3) & ~3;
  }
  int tsum = v[0] + v[1] + v[2] + v[3];
  sdata[t] = tsum;
  __syncthreads();
  for (int off = 1; off < 256; off <<= 1) {
    int x = (t >= off) ? sdata[t - off] : 0;
    __syncthreads();
    sdata[t] += x;
    __syncthreads();
  }
  int excl = sdata[t] - tsum;
  if (t == 255) blocksum[blockIdx.x] = sdata[255];
  int run = excl;
#pragma unroll
  for (int j = 0; j < 4; ++j) {
    if (base + j <= n) { row_start[base + j] = run; run += v[j]; }
  }
}

__global__ void k_scan_top(const int* __restrict__ blocksum, int* __restrict__ blockoff, int nb) {
  if (threadIdx.x == 0 && blockIdx.x == 0) {
    int run = 0;
    for (int i = 0; i < nb; ++i) { blockoff[i] = run; run += blocksum[i]; }
  }
}

__global__ void k_scan_add(int* __restrict__ row_start, const int* __restrict__ blockoff, int n) {
  int i = blockIdx.x * blockDim.x + threadIdx.x;
  if (i <= n) row_start[i] += blockoff[i >> 10];
}

// Fill padding slots (true-degree..padded-degree) with src=self, norm=0.
__global__ void k_pad(const int* __restrict__ indeg, const int* __restrict__ row_start,
                      int* __restrict__ csr_src, float* __restrict__ csr_norm, int n) {
  int i = blockIdx.x * blockDim.x + threadIdx.x;
  if (i < n) {
    int d = indeg[i];
    int p = (d + 3) & ~3;
    int b = row_start[i];
    for (int j = d; j < p; ++j) { csr_src[b + j] = i; csr_norm[b + j] = 0.f; }
  }
}

__global__ void k_scatter(const int* __restrict__ src, const int* __restrict__ dst,
                          const int* __restrict__ row_start, int* __restrict__ cursor,
                          const float* __restrict__ dinv, int* __restrict__ csr_src,
                          float* __restrict__ csr_norm, int E) {
  int e = blockIdx.x * blockDim.x + threadIdx.x;
  if (e < E) {
    int s = src[e], d = dst[e];
    int pos = atomicAdd(&cursor[d], 1);
    int idx = row_start[d] + pos;
    csr_src[idx] = s;
    csr_norm[idx] = dinv[s] * dinv[d];
  }
}

// W [K][Nc] fp32 -> transposed fp16 split: Wt_hi/Wt_lo [Nc][K], lo pre-scaled 1024.
__global__ void k_wcvt(const float* __restrict__ W, _Float16* __restrict__ Wt_hi,
                       _Float16* __restrict__ Wt_lo, int K, int Nc) {
  int i = blockIdx.x * blockDim.x + threadIdx.x;
  if (i < K * Nc) {
    int k = i / Nc, n = i % Nc;
    float v = W[i];
    _Float16 h = (_Float16)v;
    Wt_hi[(size_t)n * K + k] = h;
    Wt_lo[(size_t)n * K + k] = (_Float16)((v - (float)h) * 1024.0f);
  }
}

// GEMM1: C[M][128] = A[M][512](fp32) @ B, B transposed-split [128][512] fp16.
// Block tile 64x128: 4 waves in 2x2, wave tile 32x64 (rf=2, cf=4).
// Register double-buffered fragment loads; fused fp32->fp16 split on A.
__global__ __launch_bounds__(256) void k_gemm1(const float* __restrict__ A,
                                               const _Float16* __restrict__ Bhi,
                                               const _Float16* __restrict__ Blo,
                                               float* __restrict__ C, int M) {
  constexpr int K = NFEAT, N = NHID;
  const int wid = threadIdx.x >> 6, lane = threadIdx.x & 63;
  const int wy = wid >> 1, wx = wid & 1;
  const int r0 = blockIdx.x * 64 + wy * 32;
  const int c0 = wx * 64;
  const int lrow = lane & 15, koff = (lane >> 4) * 8;

  f32x4 acc_h[2][4] = {};
  f32x4 acc_l[2][4] = {};
  f16x8 bh[2][4], bl[2][4], ah[2][2], al[2][2];

  auto loadB = [&](int buf, int k0) {
#pragma unroll
    for (int cf = 0; cf < 4; ++cf) {
      size_t off = (size_t)(c0 + cf * 16 + lrow) * K + k0 + koff;
      bh[buf][cf] = *(const f16x8*)(Bhi + off);
      bl[buf][cf] = *(const f16x8*)(Blo + off);
    }
  };
  auto loadA = [&](int buf, int k0) {
#pragma unroll
    for (int rf = 0; rf < 2; ++rf) {
      int row = r0 + rf * 16 + lrow;
      row = row < M ? row : M - 1;
      const float* p = A + (size_t)row * K + k0 + koff;
      float4 v0 = *(const float4*)p;
      float4 v1 = *(const float4*)(p + 4);
      float vv[8] = {v0.x, v0.y, v0.z, v0.w, v1.x, v1.y, v1.z, v1.w};
#pragma unroll
      for (int j = 0; j < 8; ++j) {
        _Float16 h = (_Float16)vv[j];
        ah[buf][rf][j] = h;
        al[buf][rf][j] = (_Float16)((vv[j] - (float)h) * 1024.0f);
      }
    }
  };

  loadB(0, 0);
  loadA(0, 0);
#pragma unroll
  for (int ks = 0; ks < K / 32; ++ks) {
    const int cur = ks & 1, nxt = cur ^ 1;
    if (ks + 1 < K / 32) { loadB(nxt, (ks + 1) * 32); loadA(nxt, (ks + 1) * 32); }
#pragma unroll
    for (int rf = 0; rf < 2; ++rf)
#pragma unroll
      for (int cf = 0; cf < 4; ++cf) {
        acc_h[rf][cf] = __builtin_amdgcn_mfma_f32_16x16x32_f16(ah[cur][rf], bh[cur][cf],
                                                               acc_h[rf][cf], 0, 0, 0);
        acc_l[rf][cf] = __builtin_amdgcn_mfma_f32_16x16x32_f16(ah[cur][rf], bl[cur][cf],
                                                               acc_l[rf][cf], 0, 0, 0);
        acc_l[rf][cf] = __builtin_amdgcn_mfma_f32_16x16x32_f16(al[cur][rf], bh[cur][cf],
                                                               acc_l[rf][cf], 0, 0, 0);
      }
  }

#pragma unroll
  for (int rf = 0; rf < 2; ++rf) {
    if (r0 + rf * 16 >= M) continue;  // M % 16 == 0: frag all-valid or all-invalid
    int rbase = r0 + rf * 16 + (lane >> 4) * 4;
#pragma unroll
    for (int cf = 0; cf < 4; ++cf) {
      int col = c0 + cf * 16 + lrow;
#pragma unroll
      for (int q = 0; q < 4; ++q)
        C[(size_t)(rbase + q) * N + col] =
            acc_h[rf][cf][q] + acc_l[rf][cf][q] * (1.0f / 1024.0f);
    }
  }
}

// GEMM2: C[M][64] = A[M][128](fp16 pair) @ B, B transposed-split [64][128].
// Block tile 64x64: 4 waves stacked in M, wave tile 16x64 (cf=4).
__global__ __launch_bounds__(256) void k_gemm2(const _Float16* __restrict__ Ahi,
                                               const _Float16* __restrict__ Alo,
                                               const _Float16* __restrict__ Bhi,
                                               const _Float16* __restrict__ Blo,
                                               float* __restrict__ C, int M) {
  constexpr int K = NHID, N = NCLS;
  const int wid = threadIdx.x >> 6, lane = threadIdx.x & 63;
  const int r0 = blockIdx.x * 64 + wid * 16;
  const int lrow = lane & 15, koff = (lane >> 4) * 8;

  f32x4 acc_h[4] = {};
  f32x4 acc_l[4] = {};
  f16x8 bh[2][4], bl[2][4], ah[2], al[2];

  auto loadB = [&](int buf, int k0) {
#pragma unroll
    for (int cf = 0; cf < 4; ++cf) {
      size_t off = (size_t)(cf * 16 + lrow) * K + k0 + koff;
      bh[buf][cf] = *(const f16x8*)(Bhi + off);
      bl[buf][cf] = *(const f16x8*)(Blo + off);
    }
  };
  auto loadA = [&](int buf, int k0) {
    int row = r0 + lrow;
    row = row < M ? row : M - 1;
    size_t off = (size_t)row * K + k0 + koff;
    ah[buf] = *(const f16x8*)(Ahi + off);
    al[buf] = *(const f16x8*)(Alo + off);
  };

  loadB(0, 0);
  loadA(0, 0);
#pragma unroll
  for (int ks = 0; ks < K / 32; ++ks) {
    const int cur = ks & 1, nxt = cur ^ 1;
    if (ks + 1 < K / 32) { loadB(nxt, (ks + 1) * 32); loadA(nxt, (ks + 1) * 32); }
#pragma unroll
    for (int cf = 0; cf < 4; ++cf) {
      acc_h[cf] = __builtin_amdgcn_mfma_f32_16x16x32_f16(ah[cur], bh[cur][cf],
                                                         acc_h[cf], 0, 0, 0);
      acc_l[cf] = __builtin_amdgcn_mfma_f32_16x16x32_f16(ah[cur], bl[cur][cf],
                                                         acc_l[cf], 0, 0, 0);
      acc_l[cf] = __builtin_amdgcn_mfma_f32_16x16x32_f16(al[cur], bh[cur][cf],
                                                         acc_l[cf], 0, 0, 0);
    }
  }

  if (r0 < M) {
    int rbase = r0 + (lane >> 4) * 4;
#pragma unroll
    for (int cf = 0; cf < 4; ++cf) {
      int col = cf * 16 + lrow;
#pragma unroll
      for (int q = 0; q < 4; ++q)
        C[(size_t)(rbase + q) * N + col] = acc_h[cf][q] + acc_l[cf][q] * (1.0f / 1024.0f);
    }
  }
}

// agg for F=128: 4 nodes / 256-thread block, one wave per node, float2 lanes.
// CSR padded to multiple of 4 -> unroll 8 + optional 4, no scalar tail.
template <bool RELU, bool EMIT16>
__global__ __launch_bounds__(256) void k_agg128(
    const float* __restrict__ h, const float* __restrict__ bias,
    const int* __restrict__ row_start, const int* __restrict__ csr_src,
    const float* __restrict__ csr_norm, const float* __restrict__ dinv,
    float* __restrict__ out, _Float16* __restrict__ out_hi,
    _Float16* __restrict__ out_lo, int N) {
  int node = blockIdx.x * 4 + (threadIdx.x >> 6);
  if (node >= N) return;
  int lane = threadIdx.x & 63;
  const float2* hp = (const float2*)h;

  float dn = dinv[node];
  float2 bs = ((const float2*)bias)[lane];
  float2 sf = hp[(size_t)node * 64 + lane];
  float2 a0 = {dn * dn * sf.x + bs.x, dn * dn * sf.y + bs.y};
  float2 a1 = {0.f, 0.f}, a2 = {0.f, 0.f}, a3 = {0.f, 0.f};
  float2 a4 = {0.f, 0.f}, a5 = {0.f, 0.f}, a6 = {0.f, 0.f}, a7 = {0.f, 0.f};

  int e = row_start[node], e1 = row_start[node + 1];
#define GATH(ACC, EI)                                        \
  {                                                          \
    int s_ = csr_src[EI];                                    \
    float w_ = csr_norm[EI];                                 \
    float2 v_ = hp[(size_t)s_ * 64 + lane];                  \
    ACC.x += w_ * v_.x;                                      \
    ACC.y += w_ * v_.y;                                      \
  }
  for (; e + 8 <= e1; e += 8) {
    GATH(a0, e + 0) GATH(a1, e + 1) GATH(a2, e + 2) GATH(a3, e + 3)
    GATH(a4, e + 4) GATH(a5, e + 5) GATH(a6, e + 6) GATH(a7, e + 7)
  }
  if (e < e1) {  // exactly 4 remain (padded count % 4 == 0)
    GATH(a0, e + 0) GATH(a1, e + 1) GATH(a2, e + 2) GATH(a3, e + 3)
  }
#undef GATH
  float ax = ((a0.x + a1.x) + (a2.x + a3.x)) + ((a4.x + a5.x) + (a6.x + a7.x));
  float ay = ((a0.y + a1.y) + (a2.y + a3.y)) + ((a4.y + a5.y) + (a6.y + a7.y));
  if (RELU) { ax = fmaxf(ax, 0.f); ay = fmaxf(ay, 0.f); }
  if (EMIT16) {
    _Float16 hx = (_Float16)ax, hy = (_Float16)ay;
    f16x2 vh = {hx, hy};
    f16x2 vl = {(_Float16)((ax - (float)hx) * 1024.0f),
                (_Float16)((ay - (float)hy) * 1024.0f)};
    *(f16x2*)(out_hi + (size_t)node * 128 + lane * 2) = vh;
    *(f16x2*)(out_lo + (size_t)node * 128 + lane * 2) = vl;
  } else {
    ((float2*)out)[(size_t)node * 64 + lane] = {ax, ay};
  }
}

// agg for F=64: 4 nodes / 256-thread block, one wave per node, scalar lanes.
__global__ __launch_bounds__(256) void k_agg64(
    const float* __restrict__ h, const float* __restrict__ bias,
    const int* __restrict__ row_start, const int* __restrict__ csr_src,
    const float* __restrict__ csr_norm, const float* __restrict__ dinv,
    float* __restrict__ out, int N) {
  int node = blockIdx.x * 4 + (threadIdx.x >> 6);
  if (node >= N) return;
  int f = threadIdx.x & 63;
  float dn = dinv[node];
  float a0 = dn * dn * h[(size_t)node * 64 + f] + bias[f];
  float a1 = 0.f, a2 = 0.f, a3 = 0.f, a4 = 0.f, a5 = 0.f, a6 = 0.f, a7 = 0.f;
  int e = row_start[node], e1 = row_start[node + 1];
#define GATH(ACC, EI) ACC += csr_norm[EI] * h[(size_t)csr_src[EI] * 64 + f];
  for (; e + 8 <= e1; e += 8) {
    GATH(a0, e + 0) GATH(a1, e + 1) GATH(a2, e + 2) GATH(a3, e + 3)
    GATH(a4, e + 4) GATH(a5, e + 5) GATH(a6, e + 6) GATH(a7, e + 7)
  }
  if (e < e1) {
    GATH(a0, e + 0) GATH(a1, e + 1) GATH(a2, e + 2) GATH(a3, e + 3)
  }
#undef GATH
  out[(size_t)node * 64 + f] =
      ((a0 + a1) + (a2 + a3)) + ((a4 + a5) + (a6 + a7));
}

static inline size_t align256(size_t x) { return (x + 255) & ~(size_t)255; }

extern "C" void kernel_launch(void* const* d_in, const int* in_sizes, int n_in,
                              void* d_out, int out_size, void* d_ws, size_t ws_size,
                              hipStream_t stream) {
  const float* x = (const float*)d_in[0];
  const int* edge = (const int*)d_in[1];
  const float* W1 = (const float*)d_in[2];
  const float* b1 = (const float*)d_in[3];
  const float* W2 = (const float*)d_in[4];
  const float* b2 = (const float*)d_in[5];
  float* out = (float*)d_out;

  const int N = NNODES;
  const int E = NEDGES;
  const int EPAD = E + 3 * N + 256;  // padded CSR capacity
  const int* src = edge;
  const int* dst = edge + E;

  // workspace carve-up
  char* w = (char*)d_ws;
  int* indeg = (int*)w;            w += align256((size_t)N * 4);
  int* cursor = (int*)w;           w += align256((size_t)N * 4);
  float* dinv = (float*)w;         w += align256((size_t)N * 4);
  int* row_start = (int*)w;        w += align256((size_t)(N + 1) * 4);
  int* blocksum = (int*)w;         w += align256(64 * 4);
  int* blockoff = (int*)w;         w += align256(64 * 4);
  int* csr_src = (int*)w;          w += align256((size_t)EPAD * 4);
  float* csr_norm = (float*)w;     w += align256((size_t)EPAD * 4);
  _Float16* W1t_hi = (_Float16*)w; w += align256((size_t)NFEAT * NHID * 2);
  _Float16* W1t_lo = (_Float16*)w; w += align256((size_t)NFEAT * NHID * 2);
  _Float16* W2t_hi = (_Float16*)w; w += align256((size_t)NHID * NCLS * 2);
  _Float16* W2t_lo = (_Float16*)w; w += align256((size_t)NHID * NCLS * 2);
  float* h0 = (float*)w;           w += align256((size_t)N * NHID * 4);
  _Float16* h1_hi = (_Float16*)w;  w += align256((size_t)N * NHID * 2);
  _Float16* h1_lo = (_Float16*)w;  w += align256((size_t)N * NHID * 2);
  float* h2 = (float*)w;           w += align256((size_t)N * NCLS * 4);

  const int nblk_n = (N + 255) / 256;
  const int nblk_n1 = (N + 1 + 255) / 256;
  const int nblk_e = (E + 255) / 256;
  const int nblk_scan = (N + 1 + 1023) / 1024;

  k_zero2<<<nblk_n, 256, 0, stream>>>(indeg, cursor, N);
  k_hist<<<nblk_e, 256, 0, stream>>>(dst, indeg, E);
  k_dinv<<<nblk_n, 256, 0, stream>>>(indeg, dinv, N);
  k_scan_block<<<nblk_scan, 256, 0, stream>>>(indeg, row_start, blocksum, N);
  k_scan_top<<<1, 64, 0, stream>>>(blocksum, blockoff, nblk_scan);
  k_scan_add<<<nblk_n1, 256, 0, stream>>>(row_start, blockoff, N);
  k_pad<<<nblk_n, 256, 0, stream>>>(indeg, row_start, csr_src, csr_norm, N);
  k_scatter<<<nblk_e, 256, 0, stream>>>(src, dst, row_start, cursor, dinv,
                                        csr_src, csr_norm, E);

  k_wcvt<<<(NFEAT * NHID + 255) / 256, 256, 0, stream>>>(W1, W1t_hi, W1t_lo,
                                                         NFEAT, NHID);
  k_wcvt<<<(NHID * NCLS + 255) / 256, 256, 0, stream>>>(W2, W2t_hi, W2t_lo,
                                                        NHID, NCLS);

  // GEMM1: h0 = x @ W1   (782 blocks)
  k_gemm1<<<(N + 63) / 64, 256, 0, stream>>>(x, W1t_hi, W1t_lo, h0, N);
  // agg1: h1 = relu(Ahat*h0 + b1) -> fp16 split pair
  k_agg128<true, true><<<(N + 3) / 4, 256, 0, stream>>>(
      h0, b1, row_start, csr_src, csr_norm, dinv, nullptr, h1_hi, h1_lo, N);
  // GEMM2: h2 = h1 @ W2   (782 blocks)
  k_gemm2<<<(N + 63) / 64, 256, 0, stream>>>(h1_hi, h1_lo, W2t_hi, W2t_lo, h2, N);
  // agg2: out = Ahat*h2 + b2
  k_agg64<<<(N + 3) / 4, 256, 0, stream>>>(h2, b2, row_start, csr_src, csr_norm,
                                           dinv, out, N);
}

// Round 5
// 350.809 us; speedup vs baseline: 1.1861x; 1.1861x over previous
//
#include <hip/hip_runtime.h>

// GCN 2-layer forward for MI355X.
// R5: GEMMs rebuilt around async global_load_lds staging + 2-phase pipeline
// (T3 minimal template) + XOR-swizzled LDS (write-side pre-swizzled global
// source, read-side XOR — rule #21). fp16-split math (hi + lo/1024, 3 MFMA
// products) unchanged. CSR build: dinv fused into scan, pad fused into
// scan_add.

#define NNODES 50000
#define NEDGES 640000
#define NFEAT 512
#define NHID 128
#define NCLS 64

typedef _Float16 f16x8 __attribute__((ext_vector_type(8)));
typedef _Float16 f16x2 __attribute__((ext_vector_type(2)));
typedef float f32x4 __attribute__((ext_vector_type(4)));

__device__ __forceinline__ void g2l16(const void* g, void* s) {
  __builtin_amdgcn_global_load_lds(
      (const __attribute__((address_space(1))) void*)g,
      (__attribute__((address_space(3))) void*)s, 16, 0, 0);
}

__global__ void k_zero2(int* __restrict__ a, int* __restrict__ b, int n) {
  int i = blockIdx.x * blockDim.x + threadIdx.x;
  if (i < n) { a[i] = 0; b[i] = 0; }
}

__global__ void k_hist(const int* __restrict__ dst, int* __restrict__ indeg, int E) {
  int i = blockIdx.x * blockDim.x + threadIdx.x;
  if (i < E) atomicAdd(&indeg[dst[i]], 1);
}

// Exclusive scan over n+1 slots of PADDED degree ((d+3)&~3); also emits dinv.
__global__ void k_scan_block(const int* __restrict__ indeg, float* __restrict__ dinv,
                             int* __restrict__ row_start, int* __restrict__ blocksum,
                             int n) {
  __shared__ int sdata[256];
  int t = threadIdx.x;
  int base = blockIdx.x * 1024 + t * 4;
  int v[4];
#pragma unroll
  for (int j = 0; j < 4; ++j) {
    int idx = base + j;
    int d = (idx < n) ? indeg[idx] : 0;
    if (idx < n) dinv[idx] = 1.0f / sqrtf((float)(d + 1));
    v[j] = (d + 3) & ~3;
  }
  int tsum = v[0] + v[1] + v[2] + v[3];
  sdata[t] = tsum;
  __syncthreads();
  for (int off = 1; off < 256; off <<= 1) {
    int x = (t >= off) ? sdata[t - off] : 0;
    __syncthreads();
    sdata[t] += x;
    __syncthreads();
  }
  int excl = sdata[t] - tsum;
  if (t == 255) blocksum[blockIdx.x] = sdata[255];
  int run = excl;
#pragma unroll
  for (int j = 0; j < 4; ++j) {
    if (base + j <= n) { row_start[base + j] = run; run += v[j]; }
  }
}

__global__ void k_scan_top(const int* __restrict__ blocksum, int* __restrict__ blockoff, int nb) {
  if (threadIdx.x == 0 && blockIdx.x == 0) {
    int run = 0;
    for (int i = 0; i < nb; ++i) { blockoff[i] = run; run += blocksum[i]; }
  }
}

// Finalize row_start and fill padding slots (src=self, norm=0).
__global__ void k_scan_add(int* __restrict__ row_start, const int* __restrict__ blockoff,
                           const int* __restrict__ indeg, int* __restrict__ csr_src,
                           float* __restrict__ csr_norm, int n) {
  int i = blockIdx.x * blockDim.x + threadIdx.x;
  if (i <= n) {
    int rs = row_start[i] + blockoff[i >> 10];
    row_start[i] = rs;
    if (i < n) {
      int d = indeg[i];
      int p = (d + 3) & ~3;
      for (int j = d; j < p; ++j) { csr_src[rs + j] = i; csr_norm[rs + j] = 0.f; }
    }
  }
}

__global__ void k_scatter(const int* __restrict__ src, const int* __restrict__ dst,
                          const int* __restrict__ row_start, int* __restrict__ cursor,
                          const float* __restrict__ dinv, int* __restrict__ csr_src,
                          float* __restrict__ csr_norm, int E) {
  int e = blockIdx.x * blockDim.x + threadIdx.x;
  if (e < E) {
    int s = src[e], d = dst[e];
    int pos = atomicAdd(&cursor[d], 1);
    int idx = row_start[d] + pos;
    csr_src[idx] = s;
    csr_norm[idx] = dinv[s] * dinv[d];
  }
}

// W [K][Nc] fp32 -> transposed fp16 split: Wt_hi/Wt_lo [Nc][K], lo pre-scaled 1024.
__global__ void k_wcvt(const float* __restrict__ W, _Float16* __restrict__ Wt_hi,
                       _Float16* __restrict__ Wt_lo, int K, int Nc) {
  int i = blockIdx.x * blockDim.x + threadIdx.x;
  if (i < K * Nc) {
    int k = i / Nc, n = i % Nc;
    float v = W[i];
    _Float16 h = (_Float16)v;
    Wt_hi[(size_t)n * K + k] = h;
    Wt_lo[(size_t)n * K + k] = (_Float16)((v - (float)h) * 1024.0f);
  }
}

// GEMM1: C[M][128] = A[M][512] fp32 @ W1 (Bt split [128][512] f16).
// 256 thr / 4 waves (2Mx2N), block tile 64x128, wave tile 32x64, BK=32.
// LDS 48KB: A[2] fp32 [64][32] (XOR (r&7)<<4), Bhi/Blo[2] f16 [128][32]
// (XOR (n&3)<<4). Staged via global_load_lds with pre-swizzled global src.
__global__ __launch_bounds__(256) void k_gemm1(const float* __restrict__ A,
                                               const _Float16* __restrict__ Bhi,
                                               const _Float16* __restrict__ Blo,
                                               float* __restrict__ C, int M) {
  __shared__ char smem[49152];
  constexpr int A_OFF = 0;       // 2 x 8KB
  constexpr int BH_OFF = 16384;  // 2 x 8KB
  constexpr int BL_OFF = 32768;  // 2 x 8KB
  const int tid = threadIdx.x;
  const int wid = tid >> 6, lane = tid & 63;
  const int wy = wid >> 1, wx = wid & 1;
  const int row0 = blockIdx.x * 64;
  const int lrow = lane & 15;
  const int lkg = lane >> 4;  // k-group 0..3

  auto stage = [&](int buf, int k0) {
#pragma unroll
    for (int c = 0; c < 2; ++c) {
      int idx = c * 256 + tid;
      int row = idx >> 3;                       // 0..63
      int kq = (idx & 7) ^ (row & 7);           // 16B slot within 128B row
      int gr = row0 + row; gr = gr < M ? gr : M - 1;
      g2l16((const char*)A + (size_t)gr * 2048 + (size_t)k0 * 4 + kq * 16,
            smem + A_OFF + buf * 8192 + ((idx & ~63) << 4));
    }
#pragma unroll
    for (int c = 0; c < 2; ++c) {
      int idx = c * 256 + tid;
      int n = idx >> 2;                         // 0..127
      int kq = (idx & 3) ^ (n & 3);             // 16B slot within 64B row
      size_t so = (size_t)n * 1024 + (size_t)k0 * 2 + kq * 16;
      g2l16((const char*)Bhi + so, smem + BH_OFF + buf * 8192 + ((idx & ~63) << 4));
      g2l16((const char*)Blo + so, smem + BL_OFF + buf * 8192 + ((idx & ~63) << 4));
    }
  };

  f32x4 acc_h[2][4] = {};
  f32x4 acc_l[2][4] = {};

  stage(0, 0);
  __syncthreads();
  int cur = 0;
  constexpr int NK = NFEAT / 32;  // 16
  for (int ks = 0; ks < NK; ++ks) {
    if (ks + 1 < NK) stage(cur ^ 1, (ks + 1) * 32);

    const char* ab = smem + A_OFF + cur * 8192;
    const char* bhb = smem + BH_OFF + cur * 8192;
    const char* blb = smem + BL_OFF + cur * 8192;
    f16x8 ah[2], al[2], bh[4], bl[4];
#pragma unroll
    for (int rf = 0; rf < 2; ++rf) {
      int r = wy * 32 + rf * 16 + lrow;
      int lin = r * 128 + lkg * 32;
      int sw = (r & 7) << 4;
      float4 v0 = *(const float4*)(ab + (lin ^ sw));
      float4 v1 = *(const float4*)(ab + ((lin + 16) ^ sw));
      float vv[8] = {v0.x, v0.y, v0.z, v0.w, v1.x, v1.y, v1.z, v1.w};
#pragma unroll
      for (int j = 0; j < 8; ++j) {
        _Float16 h = (_Float16)vv[j];
        ah[rf][j] = h;
        al[rf][j] = (_Float16)((vv[j] - (float)h) * 1024.0f);
      }
    }
#pragma unroll
    for (int cf = 0; cf < 4; ++cf) {
      int n = wx * 64 + cf * 16 + lrow;
      int lin = n * 64 + lkg * 16;
      int sw = (n & 3) << 4;
      bh[cf] = *(const f16x8*)(bhb + (lin ^ sw));
      bl[cf] = *(const f16x8*)(blb + (lin ^ sw));
    }
#pragma unroll
    for (int rf = 0; rf < 2; ++rf)
#pragma unroll
      for (int cf = 0; cf < 4; ++cf) {
        acc_h[rf][cf] = __builtin_amdgcn_mfma_f32_16x16x32_f16(ah[rf], bh[cf],
                                                               acc_h[rf][cf], 0, 0, 0);
        acc_l[rf][cf] = __builtin_amdgcn_mfma_f32_16x16x32_f16(ah[rf], bl[cf],
                                                               acc_l[rf][cf], 0, 0, 0);
        acc_l[rf][cf] = __builtin_amdgcn_mfma_f32_16x16x32_f16(al[rf], bh[cf],
                                                               acc_l[rf][cf], 0, 0, 0);
      }
    if (ks + 1 < NK) { __syncthreads(); cur ^= 1; }
  }

#pragma unroll
  for (int rf = 0; rf < 2; ++rf) {
    int rfrag = row0 + wy * 32 + rf * 16;
    if (rfrag >= M) continue;  // M % 16 == 0: frag all-valid or all-invalid
    int rbase = rfrag + lkg * 4;
#pragma unroll
    for (int cf = 0; cf < 4; ++cf) {
      int col = wx * 64 + cf * 16 + lrow;
#pragma unroll
      for (int q = 0; q < 4; ++q)
        C[(size_t)(rbase + q) * NHID + col] =
            acc_h[rf][cf][q] + acc_l[rf][cf][q] * (1.0f / 1024.0f);
    }
  }
}

// GEMM2: C[M][64] = h1 (fp16 pair [M][128]) @ W2 (Bt split [64][128]).
// 256 thr / 4 waves stacked in M, block tile 64x64, wave tile 16x64, BK=32.
// LDS 32KB: Ahi/Alo[2] f16 [64][32], Bhi/Blo[2] f16 [64][32], XOR (r&3)<<4.
__global__ __launch_bounds__(256) void k_gemm2(const _Float16* __restrict__ Ahi,
                                               const _Float16* __restrict__ Alo,
                                               const _Float16* __restrict__ Bhi,
                                               const _Float16* __restrict__ Blo,
                                               float* __restrict__ C, int M) {
  __shared__ char smem[32768];
  constexpr int AH_OFF = 0;      // 2 x 4KB
  constexpr int AL_OFF = 8192;   // 2 x 4KB
  constexpr int BH_OFF = 16384;  // 2 x 4KB
  constexpr int BL_OFF = 24576;  // 2 x 4KB
  const int tid = threadIdx.x;
  const int wid = tid >> 6, lane = tid & 63;
  const int row0 = blockIdx.x * 64;
  const int lrow = lane & 15;
  const int lkg = lane >> 4;

  auto stage = [&](int buf, int k0) {
    int idx = tid;                       // 0..255 covers 4KB
    int row = idx >> 2;                  // 0..63
    int kq = (idx & 3) ^ (row & 3);
    int gr = row0 + row; gr = gr < M ? gr : M - 1;
    size_t aso = (size_t)gr * 256 + (size_t)k0 * 2 + kq * 16;
    size_t bso = (size_t)row * 256 + (size_t)k0 * 2 + kq * 16;
    int ldso = (idx & ~63) << 4;
    g2l16((const char*)Ahi + aso, smem + AH_OFF + buf * 4096 + ldso);
    g2l16((const char*)Alo + aso, smem + AL_OFF + buf * 4096 + ldso);
    g2l16((const char*)Bhi + bso, smem + BH_OFF + buf * 4096 + ldso);
    g2l16((const char*)Blo + bso, smem + BL_OFF + buf * 4096 + ldso);
  };

  f32x4 acc_h[4] = {};
  f32x4 acc_l[4] = {};

  stage(0, 0);
  __syncthreads();
  int cur = 0;
  constexpr int NK = NHID / 32;  // 4
  for (int ks = 0; ks < NK; ++ks) {
    if (ks + 1 < NK) stage(cur ^ 1, (ks + 1) * 32);

    const char* ahb = smem + AH_OFF + cur * 4096;
    const char* alb = smem + AL_OFF + cur * 4096;
    const char* bhb = smem + BH_OFF + cur * 4096;
    const char* blb = smem + BL_OFF + cur * 4096;
    int r = wid * 16 + lrow;
    int alin = r * 64 + lkg * 16;
    int asw = (r & 3) << 4;
    f16x8 ah = *(const f16x8*)(ahb + (alin ^ asw));
    f16x8 al = *(const f16x8*)(alb + (alin ^ asw));
    f16x8 bh[4], bl[4];
#pragma unroll
    for (int cf = 0; cf < 4; ++cf) {
      int n = cf * 16 + lrow;
      int lin = n * 64 + lkg * 16;
      int sw = (n & 3) << 4;
      bh[cf] = *(const f16x8*)(bhb + (lin ^ sw));
      bl[cf] = *(const f16x8*)(blb + (lin ^ sw));
    }
#pragma unroll
    for (int cf = 0; cf < 4; ++cf) {
      acc_h[cf] = __builtin_amdgcn_mfma_f32_16x16x32_f16(ah, bh[cf], acc_h[cf], 0, 0, 0);
      acc_l[cf] = __builtin_amdgcn_mfma_f32_16x16x32_f16(ah, bl[cf], acc_l[cf], 0, 0, 0);
      acc_l[cf] = __builtin_amdgcn_mfma_f32_16x16x32_f16(al, bh[cf], acc_l[cf], 0, 0, 0);
    }
    if (ks + 1 < NK) { __syncthreads(); cur ^= 1; }
  }

  int rfrag = row0 + wid * 16;
  if (rfrag < M) {
    int rbase = rfrag + lkg * 4;
#pragma unroll
    for (int cf = 0; cf < 4; ++cf) {
      int col = cf * 16 + lrow;
#pragma unroll
      for (int q = 0; q < 4; ++q)
        C[(size_t)(rbase + q) * NCLS + col] =
            acc_h[cf][q] + acc_l[cf][q] * (1.0f / 1024.0f);
    }
  }
}

// agg F=128: one wave per node, float2 lanes, 8-deep gather unroll.
template <bool RELU, bool EMIT16>
__global__ __launch_bounds__(256) void k_agg128(
    const float* __restrict__ h, const float* __restrict__ bias,
    const int* __restrict__ row_start, const int* __restrict__ csr_src,
    const float* __restrict__ csr_norm, const float* __restrict__ dinv,
    float* __restrict__ out, _Float16* __restrict__ out_hi,
    _Float16* __restrict__ out_lo, int N) {
  int node = blockIdx.x * 4 + (threadIdx.x >> 6);
  if (node >= N) return;
  int lane = threadIdx.x & 63;
  const float2* hp = (const float2*)h;

  float dn = dinv[node];
  float2 bs = ((const float2*)bias)[lane];
  float2 sf = hp[(size_t)node * 64 + lane];
  float2 a0 = {dn * dn * sf.x + bs.x, dn * dn * sf.y + bs.y};
  float2 a1 = {0.f, 0.f}, a2 = {0.f, 0.f}, a3 = {0.f, 0.f};
  float2 a4 = {0.f, 0.f}, a5 = {0.f, 0.f}, a6 = {0.f, 0.f}, a7 = {0.f, 0.f};

  int e = row_start[node], e1 = row_start[node + 1];
#define GATH(ACC, EI)                                        \
  {                                                          \
    int s_ = csr_src[EI];                                    \
    float w_ = csr_norm[EI];                                 \
    float2 v_ = hp[(size_t)s_ * 64 + lane];                  \
    ACC.x += w_ * v_.x;                                      \
    ACC.y += w_ * v_.y;                                      \
  }
  for (; e + 8 <= e1; e += 8) {
    GATH(a0, e + 0) GATH(a1, e + 1) GATH(a2, e + 2) GATH(a3, e + 3)
    GATH(a4, e + 4) GATH(a5, e + 5) GATH(a6, e + 6) GATH(a7, e + 7)
  }
  if (e < e1) {  // exactly 4 remain (padded count % 4 == 0)
    GATH(a0, e + 0) GATH(a1, e + 1) GATH(a2, e + 2) GATH(a3, e + 3)
  }
#undef GATH
  float ax = ((a0.x + a1.x) + (a2.x + a3.x)) + ((a4.x + a5.x) + (a6.x + a7.x));
  float ay = ((a0.y + a1.y) + (a2.y + a3.y)) + ((a4.y + a5.y) + (a6.y + a7.y));
  if (RELU) { ax = fmaxf(ax, 0.f); ay = fmaxf(ay, 0.f); }
  if (EMIT16) {
    _Float16 hx = (_Float16)ax, hy = (_Float16)ay;
    f16x2 vh = {hx, hy};
    f16x2 vl = {(_Float16)((ax - (float)hx) * 1024.0f),
                (_Float16)((ay - (float)hy) * 1024.0f)};
    *(f16x2*)(out_hi + (size_t)node * 128 + lane * 2) = vh;
    *(f16x2*)(out_lo + (size_t)node * 128 + lane * 2) = vl;
  } else {
    ((float2*)out)[(size_t)node * 64 + lane] = {ax, ay};
  }
}

// agg F=64: one wave per node, scalar lanes, 8-deep gather unroll.
__global__ __launch_bounds__(256) void k_agg64(
    const float* __restrict__ h, const float* __restrict__ bias,
    const int* __restrict__ row_start, const int* __restrict__ csr_src,
    const float* __restrict__ csr_norm, const float* __restrict__ dinv,
    float* __restrict__ out, int N) {
  int node = blockIdx.x * 4 + (threadIdx.x >> 6);
  if (node >= N) return;
  int f = threadIdx.x & 63;
  float dn = dinv[node];
  float a0 = dn * dn * h[(size_t)node * 64 + f] + bias[f];
  float a1 = 0.f, a2 = 0.f, a3 = 0.f, a4 = 0.f, a5 = 0.f, a6 = 0.f, a7 = 0.f;
  int e = row_start[node], e1 = row_start[node + 1];
#define GATH(ACC, EI) ACC += csr_norm[EI] * h[(size_t)csr_src[EI] * 64 + f];
  for (; e + 8 <= e1; e += 8) {
    GATH(a0, e + 0) GATH(a1, e + 1) GATH(a2, e + 2) GATH(a3, e + 3)
    GATH(a4, e + 4) GATH(a5, e + 5) GATH(a6, e + 6) GATH(a7, e + 7)
  }
  if (e < e1) {
    GATH(a0, e + 0) GATH(a1, e + 1) GATH(a2, e + 2) GATH(a3, e + 3)
  }
#undef GATH
  out[(size_t)node * 64 + f] =
      ((a0 + a1) + (a2 + a3)) + ((a4 + a5) + (a6 + a7));
}

static inline size_t align256(size_t x) { return (x + 255) & ~(size_t)255; }

extern "C" void kernel_launch(void* const* d_in, const int* in_sizes, int n_in,
                              void* d_out, int out_size, void* d_ws, size_t ws_size,
                              hipStream_t stream) {
  const float* x = (const float*)d_in[0];
  const int* edge = (const int*)d_in[1];
  const float* W1 = (const float*)d_in[2];
  const float* b1 = (const float*)d_in[3];
  const float* W2 = (const float*)d_in[4];
  const float* b2 = (const float*)d_in[5];
  float* out = (float*)d_out;

  const int N = NNODES;
  const int E = NEDGES;
  const int EPAD = E + 3 * N + 256;
  const int* src = edge;
  const int* dst = edge + E;

  char* w = (char*)d_ws;
  int* indeg = (int*)w;            w += align256((size_t)N * 4);
  int* cursor = (int*)w;           w += align256((size_t)N * 4);
  float* dinv = (float*)w;         w += align256((size_t)N * 4);
  int* row_start = (int*)w;        w += align256((size_t)(N + 1) * 4);
  int* blocksum = (int*)w;         w += align256(64 * 4);
  int* blockoff = (int*)w;         w += align256(64 * 4);
  int* csr_src = (int*)w;          w += align256((size_t)EPAD * 4);
  float* csr_norm = (float*)w;     w += align256((size_t)EPAD * 4);
  _Float16* W1t_hi = (_Float16*)w; w += align256((size_t)NFEAT * NHID * 2);
  _Float16* W1t_lo = (_Float16*)w; w += align256((size_t)NFEAT * NHID * 2);
  _Float16* W2t_hi = (_Float16*)w; w += align256((size_t)NHID * NCLS * 2);
  _Float16* W2t_lo = (_Float16*)w; w += align256((size_t)NHID * NCLS * 2);
  float* h0 = (float*)w;           w += align256((size_t)N * NHID * 4);
  _Float16* h1_hi = (_Float16*)w;  w += align256((size_t)N * NHID * 2);
  _Float16* h1_lo = (_Float16*)w;  w += align256((size_t)N * NHID * 2);
  float* h2 = (float*)w;           w += align256((size_t)N * NCLS * 4);

  const int nblk_n = (N + 255) / 256;
  const int nblk_n1 = (N + 1 + 255) / 256;
  const int nblk_e = (E + 255) / 256;
  const int nblk_scan = (N + 1 + 1023) / 1024;

  k_zero2<<<nblk_n, 256, 0, stream>>>(indeg, cursor, N);
  k_hist<<<nblk_e, 256, 0, stream>>>(dst, indeg, E);
  k_scan_block<<<nblk_scan, 256, 0, stream>>>(indeg, dinv, row_start, blocksum, N);
  k_scan_top<<<1, 64, 0, stream>>>(blocksum, blockoff, nblk_scan);
  k_scan_add<<<nblk_n1, 256, 0, stream>>>(row_start, blockoff, indeg, csr_src,
                                          csr_norm, N);
  k_scatter<<<nblk_e, 256, 0, stream>>>(src, dst, row_start, cursor, dinv,
                                        csr_src, csr_norm, E);

  k_wcvt<<<(NFEAT * NHID + 255) / 256, 256, 0, stream>>>(W1, W1t_hi, W1t_lo,
                                                         NFEAT, NHID);
  k_wcvt<<<(NHID * NCLS + 255) / 256, 256, 0, stream>>>(W2, W2t_hi, W2t_lo,
                                                        NHID, NCLS);

  // GEMM1: h0 = x @ W1 (782 blocks, LDS-staged)
  k_gemm1<<<(N + 63) / 64, 256, 0, stream>>>(x, W1t_hi, W1t_lo, h0, N);
  // agg1: h1 = relu(Ahat*h0 + b1) -> fp16 split pair
  k_agg128<true, true><<<(N + 3) / 4, 256, 0, stream>>>(
      h0, b1, row_start, csr_src, csr_norm, dinv, nullptr, h1_hi, h1_lo, N);
  // GEMM2: h2 = h1 @ W2 (782 blocks, LDS-staged)
  k_gemm2<<<(N + 63) / 64, 256, 0, stream>>>(h1_hi, h1_lo, W2t_hi, W2t_lo, h2, N);
  // agg2: out = Ahat*h2 + b2
  k_agg64<<<(N + 3) / 4, 256, 0, stream>>>(h2, b2, row_start, csr_src, csr_norm,
                                           dinv, out, N);
}